// Round 8
// baseline (138.787 us; speedup 1.0000x reference)
//
#include <hip/hip_runtime.h>
#include <stdint.h>

#define NROWS 262144
#define DDIM 128
#define NCLS 512
#define NHB 128  // hist/scatter blocks
constexpr float INV_BETA = 10.0f;

typedef __bf16 v8bf __attribute__((ext_vector_type(8)));
typedef float v4f __attribute__((ext_vector_type(4)));

__device__ inline unsigned short f2bf(float f) {
    uint32_t u = __builtin_bit_cast(uint32_t, f);
    u += 0x7FFFu + ((u >> 16) & 1u);
    return (unsigned short)(u >> 16);
}
__device__ inline float bflo(uint32_t u) { return __builtin_bit_cast(float, u << 16); }
__device__ inline float bfhi(uint32_t u) { return __builtin_bit_cast(float, u & 0xFFFF0000u); }

// K1 v3: streaming L2-normalize fp32 -> bf16. 4 independent row-chunks per iter.
__global__ __launch_bounds__(256) void k1_normalize(
    const float* __restrict__ in, unsigned short* __restrict__ xb) {
    int t = threadIdx.x;
    int w = t >> 6;
    int half = (t & 63) >> 5;
    int lane32 = t & 31;
    const int CH = NROWS / 4;  // 65536
    for (int row = blockIdx.x * 8 + w * 2 + half; row < CH; row += 2048 * 8) {
        float4 v[4];
#pragma unroll
        for (int j = 0; j < 4; ++j)
            v[j] = *reinterpret_cast<const float4*>(in + (size_t)(row + j * CH) * DDIM + lane32 * 4);
        float s[4];
#pragma unroll
        for (int j = 0; j < 4; ++j)
            s[j] = v[j].x * v[j].x + v[j].y * v[j].y + v[j].z * v[j].z + v[j].w * v[j].w;
#pragma unroll
        for (int off = 1; off < 32; off <<= 1) {
#pragma unroll
            for (int j = 0; j < 4; ++j) s[j] += __shfl_xor(s[j], off);
        }
#pragma unroll
        for (int j = 0; j < 4; ++j) {
            float iv = rsqrtf(fmaxf(s[j], 1e-24f));
            ushort4 o;
            o.x = f2bf(v[j].x * iv); o.y = f2bf(v[j].y * iv);
            o.z = f2bf(v[j].z * iv); o.w = f2bf(v[j].w * iv);
            *reinterpret_cast<ushort4*>(xb + (size_t)(row + j * CH) * DDIM + lane32 * 4) = o;
        }
    }
}

// Class histogram per block -> bh[b][c]. No global atomics.
__global__ __launch_bounds__(256) void k_hist(
    const int* __restrict__ tgt, int* __restrict__ bh) {
    __shared__ int h[NCLS];
    int t = threadIdx.x;
    for (int i = t; i < NCLS; i += 256) h[i] = 0;
    __syncthreads();
    int base = blockIdx.x * (NROWS / NHB);
    for (int i = base + t; i < base + NROWS / NHB; i += 256)
        atomicAdd(&h[tgt[i]], 1);
    __syncthreads();
    for (int i = t; i < NCLS; i += 256)
        bh[blockIdx.x * NCLS + i] = h[i];
}

// Prefix: counts from bh columns, class offsets, n_absent, per-block bases,
// and zero the output scalar. One block of 512.
__global__ __launch_bounds__(512) void k_prefix(
    const int* __restrict__ bh, int* __restrict__ counts, int* __restrict__ offs,
    int* __restrict__ base, float* __restrict__ nabsG, float* __restrict__ out) {
    __shared__ int sc[NCLS];
    __shared__ int za;
    int t = threadIdx.x;
    int cnt = 0;
    for (int b = 0; b < NHB; ++b) cnt += bh[b * NCLS + t];
    counts[t] = cnt;
    sc[t] = cnt;
    if (t == 0) za = 0;
    __syncthreads();
    for (int off = 1; off < NCLS; off <<= 1) {
        int v = (t >= off) ? sc[t - off] : 0;
        __syncthreads();
        sc[t] += v;
        __syncthreads();
    }
    int excl = sc[t] - cnt;
    offs[t] = excl;
    if (cnt == 0) atomicAdd(&za, 1);
    int run = excl;
    for (int b = 0; b < NHB; ++b) {
        base[b * NCLS + t] = run;
        run += bh[b * NCLS + t];
    }
    __syncthreads();
    if (t == 0) { *nabsG = (float)za; *out = 0.0f; }
}

// Scatter: per-block LDS cursors seeded from deterministic bases. No global atomics.
__global__ __launch_bounds__(256) void k_scatter(
    const int* __restrict__ tgt, const int* __restrict__ base, int* __restrict__ ridx) {
    __shared__ int cur[NCLS];
    int t = threadIdx.x;
    int b = blockIdx.x;
    cur[t] = base[b * NCLS + t];
    cur[t + 256] = base[b * NCLS + t + 256];
    __syncthreads();
    int r0 = b * (NROWS / NHB);
    for (int i = t; i < NROWS / NHB; i += 256) {
        int row = r0 + i;
        int c = tgt[row];
        int pos = atomicAdd(&cur[c], 1);
        ridx[pos] = row;
    }
}

// Per-class mean + L2-normalize -> bf16 centers. 1 class/block, 8 waves/class.
__global__ __launch_bounds__(512) void k_centers(
    const unsigned short* __restrict__ xb, const int* __restrict__ ridx,
    const int* __restrict__ counts, const int* __restrict__ offs,
    unsigned short* __restrict__ cen) {
    __shared__ float2 sP[8][64];
    int t = threadIdx.x, w = t >> 6, l = t & 63;
    int cl = blockIdx.x;
    int cnt = counts[cl], start = offs[cl];
    const uint32_t* xb32 = (const uint32_t*)xb;
    float a0 = 0.0f, a1 = 0.0f;
    int per = (cnt + 7) >> 3;
    int lo = w * per, hi = min(cnt, lo + per);
    int i = lo;
    for (; i + 8 <= hi; i += 8) {
        int id[8]; uint32_t v[8];
#pragma unroll
        for (int j = 0; j < 8; ++j) id[j] = ridx[start + i + j];
#pragma unroll
        for (int j = 0; j < 8; ++j) v[j] = xb32[(size_t)id[j] * 64 + l];
#pragma unroll
        for (int j = 0; j < 8; ++j) { a0 += bflo(v[j]); a1 += bfhi(v[j]); }
    }
    for (; i < hi; ++i) {
        uint32_t v = xb32[(size_t)ridx[start + i] * 64 + l];
        a0 += bflo(v); a1 += bfhi(v);
    }
    sP[w][l] = make_float2(a0, a1);
    __syncthreads();
    if (w == 0) {
        float c0 = 0.0f, c1 = 0.0f;
#pragma unroll
        for (int q = 0; q < 8; ++q) { c0 += sP[q][l].x; c1 += sP[q][l].y; }
        float fc = fmaxf((float)cnt, 1.0f);
        c0 /= fc; c1 /= fc;
        float ss = c0 * c0 + c1 * c1;
        for (int off = 1; off < 64; off <<= 1) ss += __shfl_xor(ss, off);
        float inv = 1.0f / fmaxf(sqrtf(ss), 1e-12f);
        ushort2 o;
        o.x = f2bf(c0 * inv); o.y = f2bf(c1 * inv);
        *reinterpret_cast<ushort2*>(cen + (size_t)cl * DDIM + l * 2) = o;
    }
}

// K4 v3: 256 blocks x 8 waves; wave w owns classes [w*64, w*64+64) as reg A-frags.
// 8 x-tiles of 128 samples, double-buffered 32KB LDS (XOR-swizzled), tgt in LDS,
// wave-parallel cross-wave reduce. 16 barriers total.
__global__ __launch_bounds__(512) void k4_loss(
    const unsigned short* __restrict__ xb, const unsigned short* __restrict__ cen,
    const int* __restrict__ tgt, const float* __restrict__ nabsG,
    float* __restrict__ out) {
    extern __shared__ char lds[];
    char* xL0 = lds;                        // 32768
    char* xL1 = lds + 32768;                // 32768
    float* denP = (float*)(lds + 65536);    // 8*128 f32 = 4096
    float* posP = (float*)(lds + 69632);    // 4096
    int* tgtL = (int*)(lds + 73728);        // 4096
    float* wsum = (float*)(lds + 77824);    // 32
    int t = threadIdx.x, w = t >> 6, l = t & 63;
    int lm = l & 15, lk = l >> 4;
    float nabs = *nabsG;

    v8bf afr[4][4];
#pragma unroll
    for (int m = 0; m < 4; ++m)
#pragma unroll
        for (int kc = 0; kc < 4; ++kc) {
            int arow = w * 64 + m * 16 + lm;
            afr[m][kc] = *reinterpret_cast<const v8bf*>(cen + (size_t)arow * DDIM + kc * 32 + lk * 8);
        }

    int block0 = blockIdx.x * 1024;
    tgtL[t] = tgt[block0 + t];
    tgtL[t + 512] = tgt[block0 + t + 512];

    // staging: thread t owns 64B (4 chunks) of the 32KB tile
    int srow = t >> 2;
    int sw = (srow & 7) << 4;
    int cb = (t & 3) * 64;
    int dst[4];
#pragma unroll
    for (int j = 0; j < 4; ++j) dst[j] = srow * 256 + ((cb + j * 16) ^ sw);
    const char* xbB = (const char*)xb + (size_t)block0 * 256;

    uint4 r[4];
#pragma unroll
    for (int j = 0; j < 4; ++j) r[j] = *(const uint4*)(xbB + t * 64 + j * 16);
#pragma unroll
    for (int j = 0; j < 4; ++j) *(uint4*)(xL0 + dst[j]) = r[j];
    float lossAcc = 0.0f;
    __syncthreads();

    for (int tile = 0; tile < 8; ++tile) {
        char* xc = (tile & 1) ? xL1 : xL0;
        char* xn = (tile & 1) ? xL0 : xL1;
        if (tile < 7) {
            const char* src = xbB + (size_t)(tile + 1) * 32768 + t * 64;
#pragma unroll
            for (int j = 0; j < 4; ++j) r[j] = *(const uint4*)(src + j * 16);
        }

#pragma unroll
        for (int h = 0; h < 2; ++h) {
            v4f acc[4][4];
            v4f zero = {0.0f, 0.0f, 0.0f, 0.0f};
#pragma unroll
            for (int m = 0; m < 4; ++m)
#pragma unroll
                for (int n = 0; n < 4; ++n) acc[m][n] = zero;

#pragma unroll
            for (int kc = 0; kc < 4; ++kc) {
                int kb = kc * 64 + lk * 16;
                v8bf b[4];
#pragma unroll
                for (int n = 0; n < 4; ++n) {
                    int brow = h * 64 + n * 16 + lm;
                    b[n] = *reinterpret_cast<const v8bf*>(xc + brow * 256 + (kb ^ ((brow & 7) << 4)));
                }
#pragma unroll
                for (int m = 0; m < 4; ++m)
#pragma unroll
                    for (int n = 0; n < 4; ++n)
                        acc[m][n] = __builtin_amdgcn_mfma_f32_16x16x32_bf16(afr[m][kc], b[n], acc[m][n], 0, 0, 0);
            }

#pragma unroll
            for (int n = 0; n < 4; ++n) {
                int s = h * 64 + n * 16 + lm;
                int ts = tgtL[tile * 128 + s];
                float se = 0.0f, sp = 0.0f;
#pragma unroll
                for (int m = 0; m < 4; ++m) {
#pragma unroll
                    for (int rr = 0; rr < 4; ++rr) {
                        int cls = w * 64 + m * 16 + lk * 4 + rr;
                        float logit = acc[m][n][rr] * INV_BETA;
                        se += __expf(logit);
                        if (cls == ts) sp = logit;
                    }
                }
                se += __shfl_xor(se, 16); se += __shfl_xor(se, 32);
                sp += __shfl_xor(sp, 16); sp += __shfl_xor(sp, 32);
                if (l < 16) { denP[w * 128 + s] = se; posP[w * 128 + s] = sp; }
            }
        }
        __syncthreads();
        if (tile < 7) {
#pragma unroll
            for (int j = 0; j < 4; ++j) *(uint4*)(xn + dst[j]) = r[j];
        }
        // wave-parallel reduce: wave w handles samples [w*16, w*16+16)
        if (l < 16) {
            int s = w * 16 + lm;
            float den = 0.0f, pos = 0.0f;
#pragma unroll
            for (int q = 0; q < 8; ++q) { den += denP[q * 128 + s]; pos += posP[q * 128 + s]; }
            lossAcc += __logf(den - nabs) - pos;
        }
        __syncthreads();
    }
#pragma unroll
    for (int off = 1; off < 16; off <<= 1) lossAcc += __shfl_xor(lossAcc, off);
    if (l == 0) wsum[w] = lossAcc;
    __syncthreads();
    if (t == 0) {
        float s = 0.0f;
#pragma unroll
        for (int q = 0; q < 8; ++q) s += wsum[q];
        atomicAdd(out, s * (1.0f / NROWS));
    }
}

extern "C" void kernel_launch(void* const* d_in, const int* in_sizes, int n_in,
                              void* d_out, int out_size, void* d_ws, size_t ws_size,
                              hipStream_t stream) {
    const float* in = (const float*)d_in[0];
    const int* tgt = (const int*)d_in[1];
    float* out = (float*)d_out;
    char* ws = (char*)d_ws;
    unsigned short* xb = (unsigned short*)(ws);              // 67108864 B
    int* counts = (int*)(ws + 67108864);                     // 2048 B
    int* offs = (int*)(ws + 67110912);                       // 2048 B
    float* nabsG = (float*)(ws + 67112960);                  // 256 B (pad)
    unsigned short* cen = (unsigned short*)(ws + 67115264);  // 131072 B
    int* ridx = (int*)(ws + 67246336);                       // 1048576 B
    int* bh = (int*)(ws + 68294912);                         // 262144 B
    int* base = (int*)(ws + 68557056);                       // 262144 B

    (void)hipFuncSetAttribute((const void*)k4_loss,
                              hipFuncAttributeMaxDynamicSharedMemorySize, 77856);

    hipLaunchKernelGGL(k1_normalize, dim3(2048), dim3(256), 0, stream, in, xb);
    hipLaunchKernelGGL(k_hist, dim3(NHB), dim3(256), 0, stream, tgt, bh);
    hipLaunchKernelGGL(k_prefix, dim3(1), dim3(512), 0, stream, bh, counts, offs, base, nabsG, out);
    hipLaunchKernelGGL(k_scatter, dim3(NHB), dim3(256), 0, stream, tgt, base, ridx);
    hipLaunchKernelGGL(k_centers, dim3(NCLS), dim3(512), 0, stream, xb, ridx, counts, offs, cen);
    hipLaunchKernelGGL(k4_loss, dim3(256), dim3(512), 77856, stream, xb, cen, tgt, nabsG, out);
}

// Round 10
// 122.252 us; speedup vs baseline: 1.1352x; 1.1352x over previous
//
#include <hip/hip_runtime.h>
#include <stdint.h>

#define NROWS 262144
#define DDIM 128
#define NCLS 512
#define NHB 128  // hist/scatter blocks
constexpr float INV_BETA = 10.0f;
constexpr float EXP2_SCALE = 14.426950408889634f;  // 10 * log2(e)

typedef __bf16 v8bf __attribute__((ext_vector_type(8)));
typedef float v4f __attribute__((ext_vector_type(4)));

__device__ inline unsigned short f2bf(float f) {
    uint32_t u = __builtin_bit_cast(uint32_t, f);
    u += 0x7FFFu + ((u >> 16) & 1u);
    return (unsigned short)(u >> 16);
}
__device__ inline float bflo(uint32_t u) { return __builtin_bit_cast(float, u << 16); }
__device__ inline float bfhi(uint32_t u) { return __builtin_bit_cast(float, u & 0xFFFF0000u); }

// K1 v3: streaming L2-normalize fp32 -> bf16. 4 independent row-chunks per iter.
__global__ __launch_bounds__(256) void k1_normalize(
    const float* __restrict__ in, unsigned short* __restrict__ xb) {
    int t = threadIdx.x;
    int w = t >> 6;
    int half = (t & 63) >> 5;
    int lane32 = t & 31;
    const int CH = NROWS / 4;  // 65536
    for (int row = blockIdx.x * 8 + w * 2 + half; row < CH; row += 2048 * 8) {
        float4 v[4];
#pragma unroll
        for (int j = 0; j < 4; ++j)
            v[j] = *reinterpret_cast<const float4*>(in + (size_t)(row + j * CH) * DDIM + lane32 * 4);
        float s[4];
#pragma unroll
        for (int j = 0; j < 4; ++j)
            s[j] = v[j].x * v[j].x + v[j].y * v[j].y + v[j].z * v[j].z + v[j].w * v[j].w;
#pragma unroll
        for (int off = 1; off < 32; off <<= 1) {
#pragma unroll
            for (int j = 0; j < 4; ++j) s[j] += __shfl_xor(s[j], off);
        }
#pragma unroll
        for (int j = 0; j < 4; ++j) {
            float iv = rsqrtf(fmaxf(s[j], 1e-24f));
            ushort4 o;
            o.x = f2bf(v[j].x * iv); o.y = f2bf(v[j].y * iv);
            o.z = f2bf(v[j].z * iv); o.w = f2bf(v[j].w * iv);
            *reinterpret_cast<ushort4*>(xb + (size_t)(row + j * CH) * DDIM + lane32 * 4) = o;
        }
    }
}

// Class histogram per block -> bh[b][c]. No global atomics.
__global__ __launch_bounds__(256) void k_hist(
    const int* __restrict__ tgt, int* __restrict__ bh) {
    __shared__ int h[NCLS];
    int t = threadIdx.x;
    for (int i = t; i < NCLS; i += 256) h[i] = 0;
    __syncthreads();
    int base = blockIdx.x * (NROWS / NHB);
    for (int i = base + t; i < base + NROWS / NHB; i += 256)
        atomicAdd(&h[tgt[i]], 1);
    __syncthreads();
    for (int i = t; i < NCLS; i += 256)
        bh[blockIdx.x * NCLS + i] = h[i];
}

// Prefix: counts, class offsets, n_absent, per-block bases; zero out.
__global__ __launch_bounds__(512) void k_prefix(
    const int* __restrict__ bh, int* __restrict__ counts, int* __restrict__ offs,
    int* __restrict__ base, float* __restrict__ nabsG, float* __restrict__ out) {
    __shared__ int sc[NCLS];
    __shared__ int za;
    int t = threadIdx.x;
    int cnt = 0;
    for (int b = 0; b < NHB; ++b) cnt += bh[b * NCLS + t];
    counts[t] = cnt;
    sc[t] = cnt;
    if (t == 0) za = 0;
    __syncthreads();
    for (int off = 1; off < NCLS; off <<= 1) {
        int v = (t >= off) ? sc[t - off] : 0;
        __syncthreads();
        sc[t] += v;
        __syncthreads();
    }
    int excl = sc[t] - cnt;
    offs[t] = excl;
    if (cnt == 0) atomicAdd(&za, 1);
    int run = excl;
    for (int b = 0; b < NHB; ++b) {
        base[b * NCLS + t] = run;
        run += bh[b * NCLS + t];
    }
    __syncthreads();
    if (t == 0) { *nabsG = (float)za; *out = 0.0f; }
}

// Scatter: per-block LDS cursors seeded from deterministic bases.
__global__ __launch_bounds__(256) void k_scatter(
    const int* __restrict__ tgt, const int* __restrict__ base, int* __restrict__ ridx) {
    __shared__ int cur[NCLS];
    int t = threadIdx.x;
    int b = blockIdx.x;
    cur[t] = base[b * NCLS + t];
    cur[t + 256] = base[b * NCLS + t + 256];
    __syncthreads();
    int r0 = b * (NROWS / NHB);
    for (int i = t; i < NROWS / NHB; i += 256) {
        int row = r0 + i;
        int c = tgt[row];
        int pos = atomicAdd(&cur[c], 1);
        ridx[pos] = row;
    }
}

// Per-class mean + L2-normalize -> bf16 centers. Also contributes the analytic
// pos-sum: sum_s pos_s = (1/beta) * sum_c cnt_c * ||cmean_c||, subtracted into out.
__global__ __launch_bounds__(512) void k_centers(
    const unsigned short* __restrict__ xb, const int* __restrict__ ridx,
    const int* __restrict__ counts, const int* __restrict__ offs,
    unsigned short* __restrict__ cen, float* __restrict__ out) {
    __shared__ float2 sP[8][64];
    int t = threadIdx.x, w = t >> 6, l = t & 63;
    int cl = blockIdx.x;
    int cnt = counts[cl], start = offs[cl];
    const uint32_t* xb32 = (const uint32_t*)xb;
    float a0 = 0.0f, a1 = 0.0f;
    int per = (cnt + 7) >> 3;
    int lo = w * per, hi = min(cnt, lo + per);
    int i = lo;
    for (; i + 8 <= hi; i += 8) {
        int id[8]; uint32_t v[8];
#pragma unroll
        for (int j = 0; j < 8; ++j) id[j] = ridx[start + i + j];
#pragma unroll
        for (int j = 0; j < 8; ++j) v[j] = xb32[(size_t)id[j] * 64 + l];
#pragma unroll
        for (int j = 0; j < 8; ++j) { a0 += bflo(v[j]); a1 += bfhi(v[j]); }
    }
    for (; i < hi; ++i) {
        uint32_t v = xb32[(size_t)ridx[start + i] * 64 + l];
        a0 += bflo(v); a1 += bfhi(v);
    }
    sP[w][l] = make_float2(a0, a1);
    __syncthreads();
    if (w == 0) {
        float c0 = 0.0f, c1 = 0.0f;
#pragma unroll
        for (int q = 0; q < 8; ++q) { c0 += sP[q][l].x; c1 += sP[q][l].y; }
        float fc = fmaxf((float)cnt, 1.0f);
        c0 /= fc; c1 /= fc;
        float ss = c0 * c0 + c1 * c1;
        for (int off = 1; off < 64; off <<= 1) ss += __shfl_xor(ss, off);
        float inv = 1.0f / fmaxf(sqrtf(ss), 1e-12f);
        ushort2 o;
        o.x = f2bf(c0 * inv); o.y = f2bf(c1 * inv);
        *reinterpret_cast<ushort2*>(cen + (size_t)cl * DDIM + l * 2) = o;
        if (l == 0)
            atomicAdd(out, -(float)cnt * sqrtf(ss) * (INV_BETA / (float)NROWS));
    }
}

// K4 v4: 256 blocks x 16 waves (1024 thr). Wave w owns 32 classes as reg A-frags.
// 8 x-tiles of 128 samples, double-buffered 32KB LDS (XOR-swizzled).
// Epilogue: den only (no pos) via exp2(acc * 10*log2e). ~100 VGPR -> 4 waves/SIMD.
__global__ __launch_bounds__(1024) void k4_loss(
    const unsigned short* __restrict__ xb, const unsigned short* __restrict__ cen,
    const float* __restrict__ nabsG, float* __restrict__ out) {
    extern __shared__ char lds[];
    char* xL0 = lds;                        // 32768
    char* xL1 = lds + 32768;                // 32768
    float* denP = (float*)(lds + 65536);    // 16*128 f32 = 8192
    float* wsum = (float*)(lds + 73728);    // 2 f32
    int t = threadIdx.x, w = t >> 6, l = t & 63;
    int lm = l & 15, lk = l >> 4;
    float nabs = *nabsG;

    v8bf afr[2][4];
#pragma unroll
    for (int m = 0; m < 2; ++m)
#pragma unroll
        for (int kc = 0; kc < 4; ++kc) {
            int arow = w * 32 + m * 16 + lm;
            afr[m][kc] = *reinterpret_cast<const v8bf*>(cen + (size_t)arow * DDIM + kc * 32 + lk * 8);
        }

    int block0 = blockIdx.x * 1024;
    // staging: thread t owns 32B (chunks 2t, 2t+1) of the 32KB tile
    int srow = t >> 3;
    int sw = (srow & 7) << 4;
    int c16 = (t & 7) * 2;
    int dst0 = srow * 256 + ((c16 * 16) ^ sw);
    int dst1 = srow * 256 + (((c16 + 1) * 16) ^ sw);
    const char* xbB = (const char*)xb + (size_t)block0 * 256;

    uint4 r0 = *(const uint4*)(xbB + t * 32);
    uint4 r1 = *(const uint4*)(xbB + t * 32 + 16);
    *(uint4*)(xL0 + dst0) = r0;
    *(uint4*)(xL0 + dst1) = r1;
    float lossAcc = 0.0f;
    __syncthreads();

    for (int tile = 0; tile < 8; ++tile) {
        char* xc = (tile & 1) ? xL1 : xL0;
        char* xn = (tile & 1) ? xL0 : xL1;
        if (tile < 7) {
            const char* src = xbB + (size_t)(tile + 1) * 32768 + t * 32;
            r0 = *(const uint4*)(src);
            r1 = *(const uint4*)(src + 16);
        }

#pragma unroll
        for (int h = 0; h < 2; ++h) {
            v4f acc[2][4];
            v4f zero = {0.0f, 0.0f, 0.0f, 0.0f};
#pragma unroll
            for (int m = 0; m < 2; ++m)
#pragma unroll
                for (int n = 0; n < 4; ++n) acc[m][n] = zero;

#pragma unroll
            for (int kc = 0; kc < 4; ++kc) {
                int kb = kc * 64 + lk * 16;
                v8bf b[4];
#pragma unroll
                for (int n = 0; n < 4; ++n) {
                    int brow = h * 64 + n * 16 + lm;
                    b[n] = *reinterpret_cast<const v8bf*>(xc + brow * 256 + (kb ^ ((brow & 7) << 4)));
                }
#pragma unroll
                for (int m = 0; m < 2; ++m)
#pragma unroll
                    for (int n = 0; n < 4; ++n)
                        acc[m][n] = __builtin_amdgcn_mfma_f32_16x16x32_bf16(afr[m][kc], b[n], acc[m][n], 0, 0, 0);
            }

#pragma unroll
            for (int n = 0; n < 4; ++n) {
                float se = 0.0f;
#pragma unroll
                for (int m = 0; m < 2; ++m) {
#pragma unroll
                    for (int rr = 0; rr < 4; ++rr)
                        se += __builtin_amdgcn_exp2f(acc[m][n][rr] * EXP2_SCALE);
                }
                se += __shfl_xor(se, 16); se += __shfl_xor(se, 32);
                if (l < 16) denP[w * 128 + h * 64 + n * 16 + lm] = se;
            }
        }
        __syncthreads();
        if (tile < 7) {
            *(uint4*)(xn + dst0) = r0;
            *(uint4*)(xn + dst1) = r1;
        }
        if (t < 128) {
            float den = 0.0f;
#pragma unroll
            for (int q = 0; q < 16; ++q) den += denP[q * 128 + t];
            lossAcc += __logf(den - nabs);
        }
        __syncthreads();
    }
    if (t < 128) {
#pragma unroll
        for (int off = 1; off < 64; off <<= 1) lossAcc += __shfl_xor(lossAcc, off);
        if (l == 0) wsum[w] = lossAcc;
    }
    __syncthreads();
    if (t == 0) atomicAdd(out, (wsum[0] + wsum[1]) * (1.0f / NROWS));
}

extern "C" void kernel_launch(void* const* d_in, const int* in_sizes, int n_in,
                              void* d_out, int out_size, void* d_ws, size_t ws_size,
                              hipStream_t stream) {
    const float* in = (const float*)d_in[0];
    const int* tgt = (const int*)d_in[1];
    float* out = (float*)d_out;
    char* ws = (char*)d_ws;
    unsigned short* xb = (unsigned short*)(ws);              // 67108864 B
    int* counts = (int*)(ws + 67108864);                     // 2048 B
    int* offs = (int*)(ws + 67110912);                       // 2048 B
    float* nabsG = (float*)(ws + 67112960);                  // 256 B (pad)
    unsigned short* cen = (unsigned short*)(ws + 67115264);  // 131072 B
    int* ridx = (int*)(ws + 67246336);                       // 1048576 B
    int* bh = (int*)(ws + 68294912);                         // 262144 B
    int* base = (int*)(ws + 68557056);                       // 262144 B

    (void)hipFuncSetAttribute((const void*)k4_loss,
                              hipFuncAttributeMaxDynamicSharedMemorySize, 73792);

    hipLaunchKernelGGL(k1_normalize, dim3(2048), dim3(256), 0, stream, in, xb);
    hipLaunchKernelGGL(k_hist, dim3(NHB), dim3(256), 0, stream, tgt, bh);
    hipLaunchKernelGGL(k_prefix, dim3(1), dim3(512), 0, stream, bh, counts, offs, base, nabsG, out);
    hipLaunchKernelGGL(k_scatter, dim3(NHB), dim3(256), 0, stream, tgt, base, ridx);
    hipLaunchKernelGGL(k_centers, dim3(NCLS), dim3(512), 0, stream, xb, ridx, counts, offs, cen, out);
    hipLaunchKernelGGL(k4_loss, dim3(256), dim3(1024), 73792, stream, xb, cen, nabsG, out);
}

// Round 11
// 115.588 us; speedup vs baseline: 1.2007x; 1.0577x over previous
//
#include <hip/hip_runtime.h>
#include <stdint.h>

#define NROWS 262144
#define DDIM 128
#define NCLS 512
#define NHB 64  // hist/scatter blocks
constexpr float INV_BETA = 10.0f;
constexpr float EXP2_SCALE = 14.426950408889634f;  // 10 * log2(e)

typedef __bf16 v8bf __attribute__((ext_vector_type(8)));
typedef float v4f __attribute__((ext_vector_type(4)));

__device__ inline unsigned short f2bf(float f) {
    uint32_t u = __builtin_bit_cast(uint32_t, f);
    u += 0x7FFFu + ((u >> 16) & 1u);
    return (unsigned short)(u >> 16);
}
__device__ inline float bflo(uint32_t u) { return __builtin_bit_cast(float, u << 16); }
__device__ inline float bfhi(uint32_t u) { return __builtin_bit_cast(float, u & 0xFFFF0000u); }

// K1 v4: streaming L2-normalize fp32 -> bf16. Each half-wave owns 4 CONSECUTIVE
// rows (contiguous 2KB read / 1KB write window). Single sweep, grid 8192.
__global__ __launch_bounds__(256) void k1_normalize(
    const float* __restrict__ in, unsigned short* __restrict__ xb) {
    int t = threadIdx.x;
    int w = t >> 6;
    int half = (t & 63) >> 5;
    int lane32 = t & 31;
    int hw = blockIdx.x * 8 + w * 2 + half;  // half-wave id, 0..65535
    int r0 = hw * 4;
    float4 v[4];
#pragma unroll
    for (int j = 0; j < 4; ++j)
        v[j] = *reinterpret_cast<const float4*>(in + (size_t)(r0 + j) * DDIM + lane32 * 4);
    float s[4];
#pragma unroll
    for (int j = 0; j < 4; ++j)
        s[j] = v[j].x * v[j].x + v[j].y * v[j].y + v[j].z * v[j].z + v[j].w * v[j].w;
#pragma unroll
    for (int off = 1; off < 32; off <<= 1) {
#pragma unroll
        for (int j = 0; j < 4; ++j) s[j] += __shfl_xor(s[j], off);
    }
#pragma unroll
    for (int j = 0; j < 4; ++j) {
        float iv = rsqrtf(fmaxf(s[j], 1e-24f));
        ushort4 o;
        o.x = f2bf(v[j].x * iv); o.y = f2bf(v[j].y * iv);
        o.z = f2bf(v[j].z * iv); o.w = f2bf(v[j].w * iv);
        *reinterpret_cast<ushort4*>(xb + (size_t)(r0 + j) * DDIM + lane32 * 4) = o;
    }
}

// Class histogram per block -> bh[b][c]. No global atomics.
__global__ __launch_bounds__(256) void k_hist(
    const int* __restrict__ tgt, int* __restrict__ bh) {
    __shared__ int h[NCLS];
    int t = threadIdx.x;
    for (int i = t; i < NCLS; i += 256) h[i] = 0;
    __syncthreads();
    int base = blockIdx.x * (NROWS / NHB);
    for (int i = base + t; i < base + NROWS / NHB; i += 256)
        atomicAdd(&h[tgt[i]], 1);
    __syncthreads();
    for (int i = t; i < NCLS; i += 256)
        bh[blockIdx.x * NCLS + i] = h[i];
}

// Prefix: counts, class offsets, n_absent, per-block bases; zero out.
__global__ __launch_bounds__(512) void k_prefix(
    const int* __restrict__ bh, int* __restrict__ counts, int* __restrict__ offs,
    int* __restrict__ base, float* __restrict__ nabsG, float* __restrict__ out) {
    __shared__ int sc[NCLS];
    __shared__ int za;
    int t = threadIdx.x;
    int cnt = 0;
#pragma unroll 8
    for (int b = 0; b < NHB; ++b) cnt += bh[b * NCLS + t];
    counts[t] = cnt;
    sc[t] = cnt;
    if (t == 0) za = 0;
    __syncthreads();
    for (int off = 1; off < NCLS; off <<= 1) {
        int v = (t >= off) ? sc[t - off] : 0;
        __syncthreads();
        sc[t] += v;
        __syncthreads();
    }
    int excl = sc[t] - cnt;
    offs[t] = excl;
    if (cnt == 0) atomicAdd(&za, 1);
    int run = excl;
    for (int b = 0; b < NHB; ++b) {
        base[b * NCLS + t] = run;
        run += bh[b * NCLS + t];
    }
    __syncthreads();
    if (t == 0) { *nabsG = (float)za; *out = 0.0f; }
}

// Scatter: per-block LDS cursors seeded from deterministic bases.
__global__ __launch_bounds__(256) void k_scatter(
    const int* __restrict__ tgt, const int* __restrict__ base, int* __restrict__ ridx) {
    __shared__ int cur[NCLS];
    int t = threadIdx.x;
    int b = blockIdx.x;
    cur[t] = base[b * NCLS + t];
    cur[t + 256] = base[b * NCLS + t + 256];
    __syncthreads();
    int r0 = b * (NROWS / NHB);
    for (int i = t; i < NROWS / NHB; i += 256) {
        int row = r0 + i;
        int c = tgt[row];
        int pos = atomicAdd(&cur[c], 1);
        ridx[pos] = row;
    }
}

// Per-class mean + L2-normalize -> bf16 centers. Also contributes the analytic
// pos-sum: sum_s pos_s = (1/beta) * sum_c cnt_c * ||cmean_c||, subtracted into out.
__global__ __launch_bounds__(512) void k_centers(
    const unsigned short* __restrict__ xb, const int* __restrict__ ridx,
    const int* __restrict__ counts, const int* __restrict__ offs,
    unsigned short* __restrict__ cen, float* __restrict__ out) {
    __shared__ float2 sP[8][64];
    int t = threadIdx.x, w = t >> 6, l = t & 63;
    int cl = blockIdx.x;
    int cnt = counts[cl], start = offs[cl];
    const uint32_t* xb32 = (const uint32_t*)xb;
    float a0 = 0.0f, a1 = 0.0f;
    int per = (cnt + 7) >> 3;
    int lo = w * per, hi = min(cnt, lo + per);
    int i = lo;
    for (; i + 8 <= hi; i += 8) {
        int id[8]; uint32_t v[8];
#pragma unroll
        for (int j = 0; j < 8; ++j) id[j] = ridx[start + i + j];
#pragma unroll
        for (int j = 0; j < 8; ++j) v[j] = xb32[(size_t)id[j] * 64 + l];
#pragma unroll
        for (int j = 0; j < 8; ++j) { a0 += bflo(v[j]); a1 += bfhi(v[j]); }
    }
    for (; i < hi; ++i) {
        uint32_t v = xb32[(size_t)ridx[start + i] * 64 + l];
        a0 += bflo(v); a1 += bfhi(v);
    }
    sP[w][l] = make_float2(a0, a1);
    __syncthreads();
    if (w == 0) {
        float c0 = 0.0f, c1 = 0.0f;
#pragma unroll
        for (int q = 0; q < 8; ++q) { c0 += sP[q][l].x; c1 += sP[q][l].y; }
        float fc = fmaxf((float)cnt, 1.0f);
        c0 /= fc; c1 /= fc;
        float ss = c0 * c0 + c1 * c1;
        for (int off = 1; off < 64; off <<= 1) ss += __shfl_xor(ss, off);
        float inv = 1.0f / fmaxf(sqrtf(ss), 1e-12f);
        ushort2 o;
        o.x = f2bf(c0 * inv); o.y = f2bf(c1 * inv);
        *reinterpret_cast<ushort2*>(cen + (size_t)cl * DDIM + l * 2) = o;
        if (l == 0)
            atomicAdd(out, -(float)cnt * sqrtf(ss) * (INV_BETA / (float)NROWS));
    }
}

// K4 v4: 256 blocks x 16 waves (1024 thr). Wave w owns 32 classes as reg A-frags.
// 8 x-tiles of 128 samples, double-buffered 32KB LDS (XOR-swizzled).
// Epilogue: den only (no pos) via exp2(acc * 10*log2e). 128 VGPR -> 4 waves/SIMD.
__global__ __launch_bounds__(1024) void k4_loss(
    const unsigned short* __restrict__ xb, const unsigned short* __restrict__ cen,
    const float* __restrict__ nabsG, float* __restrict__ out) {
    extern __shared__ char lds[];
    char* xL0 = lds;                        // 32768
    char* xL1 = lds + 32768;                // 32768
    float* denP = (float*)(lds + 65536);    // 16*128 f32 = 8192
    float* wsum = (float*)(lds + 73728);    // 2 f32
    int t = threadIdx.x, w = t >> 6, l = t & 63;
    int lm = l & 15, lk = l >> 4;
    float nabs = *nabsG;

    v8bf afr[2][4];
#pragma unroll
    for (int m = 0; m < 2; ++m)
#pragma unroll
        for (int kc = 0; kc < 4; ++kc) {
            int arow = w * 32 + m * 16 + lm;
            afr[m][kc] = *reinterpret_cast<const v8bf*>(cen + (size_t)arow * DDIM + kc * 32 + lk * 8);
        }

    int block0 = blockIdx.x * 1024;
    // staging: thread t owns 32B (chunks 2t, 2t+1) of the 32KB tile
    int srow = t >> 3;
    int sw = (srow & 7) << 4;
    int c16 = (t & 7) * 2;
    int dst0 = srow * 256 + ((c16 * 16) ^ sw);
    int dst1 = srow * 256 + (((c16 + 1) * 16) ^ sw);
    const char* xbB = (const char*)xb + (size_t)block0 * 256;

    uint4 r0 = *(const uint4*)(xbB + t * 32);
    uint4 r1 = *(const uint4*)(xbB + t * 32 + 16);
    *(uint4*)(xL0 + dst0) = r0;
    *(uint4*)(xL0 + dst1) = r1;
    float lossAcc = 0.0f;
    __syncthreads();

    for (int tile = 0; tile < 8; ++tile) {
        char* xc = (tile & 1) ? xL1 : xL0;
        char* xn = (tile & 1) ? xL0 : xL1;
        if (tile < 7) {
            const char* src = xbB + (size_t)(tile + 1) * 32768 + t * 32;
            r0 = *(const uint4*)(src);
            r1 = *(const uint4*)(src + 16);
        }

#pragma unroll
        for (int h = 0; h < 2; ++h) {
            v4f acc[2][4];
            v4f zero = {0.0f, 0.0f, 0.0f, 0.0f};
#pragma unroll
            for (int m = 0; m < 2; ++m)
#pragma unroll
                for (int n = 0; n < 4; ++n) acc[m][n] = zero;

#pragma unroll
            for (int kc = 0; kc < 4; ++kc) {
                int kb = kc * 64 + lk * 16;
                v8bf b[4];
#pragma unroll
                for (int n = 0; n < 4; ++n) {
                    int brow = h * 64 + n * 16 + lm;
                    b[n] = *reinterpret_cast<const v8bf*>(xc + brow * 256 + (kb ^ ((brow & 7) << 4)));
                }
#pragma unroll
                for (int m = 0; m < 2; ++m)
#pragma unroll
                    for (int n = 0; n < 4; ++n)
                        acc[m][n] = __builtin_amdgcn_mfma_f32_16x16x32_bf16(afr[m][kc], b[n], acc[m][n], 0, 0, 0);
            }

#pragma unroll
            for (int n = 0; n < 4; ++n) {
                float se = 0.0f;
#pragma unroll
                for (int m = 0; m < 2; ++m) {
#pragma unroll
                    for (int rr = 0; rr < 4; ++rr)
                        se += __builtin_amdgcn_exp2f(acc[m][n][rr] * EXP2_SCALE);
                }
                se += __shfl_xor(se, 16); se += __shfl_xor(se, 32);
                if (l < 16) denP[w * 128 + h * 64 + n * 16 + lm] = se;
            }
        }
        __syncthreads();
        if (tile < 7) {
            *(uint4*)(xn + dst0) = r0;
            *(uint4*)(xn + dst1) = r1;
        }
        if (t < 128) {
            float den = 0.0f;
#pragma unroll
            for (int q = 0; q < 16; ++q) den += denP[q * 128 + t];
            lossAcc += __logf(den - nabs);
        }
        __syncthreads();
    }
    if (t < 128) {
#pragma unroll
        for (int off = 1; off < 64; off <<= 1) lossAcc += __shfl_xor(lossAcc, off);
        if (l == 0) wsum[w] = lossAcc;
    }
    __syncthreads();
    if (t == 0) atomicAdd(out, (wsum[0] + wsum[1]) * (1.0f / NROWS));
}

extern "C" void kernel_launch(void* const* d_in, const int* in_sizes, int n_in,
                              void* d_out, int out_size, void* d_ws, size_t ws_size,
                              hipStream_t stream) {
    const float* in = (const float*)d_in[0];
    const int* tgt = (const int*)d_in[1];
    float* out = (float*)d_out;
    char* ws = (char*)d_ws;
    unsigned short* xb = (unsigned short*)(ws);              // 67108864 B
    int* counts = (int*)(ws + 67108864);                     // 2048 B
    int* offs = (int*)(ws + 67110912);                       // 2048 B
    float* nabsG = (float*)(ws + 67112960);                  // 256 B (pad)
    unsigned short* cen = (unsigned short*)(ws + 67115264);  // 131072 B
    int* ridx = (int*)(ws + 67246336);                       // 1048576 B
    int* bh = (int*)(ws + 68294912);                         // 131072 B (NHB=64)
    int* base = (int*)(ws + 68557056);                       // 131072 B

    (void)hipFuncSetAttribute((const void*)k4_loss,
                              hipFuncAttributeMaxDynamicSharedMemorySize, 73792);

    hipLaunchKernelGGL(k1_normalize, dim3(8192), dim3(256), 0, stream, in, xb);
    hipLaunchKernelGGL(k_hist, dim3(NHB), dim3(256), 0, stream, tgt, bh);
    hipLaunchKernelGGL(k_prefix, dim3(1), dim3(512), 0, stream, bh, counts, offs, base, nabsG, out);
    hipLaunchKernelGGL(k_scatter, dim3(NHB), dim3(256), 0, stream, tgt, base, ridx);
    hipLaunchKernelGGL(k_centers, dim3(NCLS), dim3(512), 0, stream, xb, ridx, counts, offs, cen, out);
    hipLaunchKernelGGL(k4_loss, dim3(256), dim3(1024), 73792, stream, xb, cen, nabsG, out);
}

// Round 13
// 112.841 us; speedup vs baseline: 1.2299x; 1.0243x over previous
//
#include <hip/hip_runtime.h>
#include <stdint.h>

#define NROWS 262144
#define DDIM 128
#define NCLS 512
#define NHB 64  // hist/scatter blocks
constexpr float INV_BETA = 10.0f;
constexpr float EXP2_SCALE = 14.426950408889634f;  // 10 * log2(e)

typedef __bf16 v8bf __attribute__((ext_vector_type(8)));
typedef float v4f __attribute__((ext_vector_type(4)));

__device__ inline unsigned short f2bf(float f) {
    uint32_t u = __builtin_bit_cast(uint32_t, f);
    u += 0x7FFFu + ((u >> 16) & 1u);
    return (unsigned short)(u >> 16);
}
__device__ inline float bflo(uint32_t u) { return __builtin_bit_cast(float, u << 16); }
__device__ inline float bfhi(uint32_t u) { return __builtin_bit_cast(float, u & 0xFFFF0000u); }

// global_load_lds: wave-uniform LDS base + lane*16; pre-swizzled global source.
#define GLL16(gsrc, ldst)                                                        \
    __builtin_amdgcn_global_load_lds(                                            \
        (const __attribute__((address_space(1))) void*)(uintptr_t)(gsrc),        \
        (__attribute__((address_space(3))) void*)(uintptr_t)(ldst), 16, 0, 0)

// K1 v5: streaming L2-normalize fp32 -> bf16 (blocks 0..8191); class histogram
// fused as blocks 8192..8192+NHB-1 (independent work, overlaps k1's tail).
__global__ __launch_bounds__(256) void k1_normalize(
    const float* __restrict__ in, const int* __restrict__ tgt,
    unsigned short* __restrict__ xb, int* __restrict__ bh) {
    __shared__ int h[NCLS];
    int t = threadIdx.x;
    if (blockIdx.x >= 8192) {
        int b = blockIdx.x - 8192;
        for (int i = t; i < NCLS; i += 256) h[i] = 0;
        __syncthreads();
        int base = b * (NROWS / NHB);
        for (int i = base + t; i < base + NROWS / NHB; i += 256)
            atomicAdd(&h[tgt[i]], 1);
        __syncthreads();
        for (int i = t; i < NCLS; i += 256)
            bh[b * NCLS + i] = h[i];
        return;
    }
    int w = t >> 6;
    int half = (t & 63) >> 5;
    int lane32 = t & 31;
    int hw = blockIdx.x * 8 + w * 2 + half;  // half-wave id, 0..65535
    int r0 = hw * 4;
    float4 v[4];
#pragma unroll
    for (int j = 0; j < 4; ++j)
        v[j] = *reinterpret_cast<const float4*>(in + (size_t)(r0 + j) * DDIM + lane32 * 4);
    float s[4];
#pragma unroll
    for (int j = 0; j < 4; ++j)
        s[j] = v[j].x * v[j].x + v[j].y * v[j].y + v[j].z * v[j].z + v[j].w * v[j].w;
#pragma unroll
    for (int off = 1; off < 32; off <<= 1) {
#pragma unroll
        for (int j = 0; j < 4; ++j) s[j] += __shfl_xor(s[j], off);
    }
#pragma unroll
    for (int j = 0; j < 4; ++j) {
        float iv = rsqrtf(fmaxf(s[j], 1e-24f));
        ushort4 o;
        o.x = f2bf(v[j].x * iv); o.y = f2bf(v[j].y * iv);
        o.z = f2bf(v[j].z * iv); o.w = f2bf(v[j].w * iv);
        *reinterpret_cast<ushort4*>(xb + (size_t)(r0 + j) * DDIM + lane32 * 4) = o;
    }
}

// Prefix: counts, class offsets, n_absent, per-block bases; zero out.
__global__ __launch_bounds__(512) void k_prefix(
    const int* __restrict__ bh, int* __restrict__ counts, int* __restrict__ offs,
    int* __restrict__ base, float* __restrict__ nabsG, float* __restrict__ out) {
    __shared__ int sc[NCLS];
    __shared__ int za;
    int t = threadIdx.x;
    int cnt = 0;
#pragma unroll 8
    for (int b = 0; b < NHB; ++b) cnt += bh[b * NCLS + t];
    counts[t] = cnt;
    sc[t] = cnt;
    if (t == 0) za = 0;
    __syncthreads();
    for (int off = 1; off < NCLS; off <<= 1) {
        int v = (t >= off) ? sc[t - off] : 0;
        __syncthreads();
        sc[t] += v;
        __syncthreads();
    }
    int excl = sc[t] - cnt;
    offs[t] = excl;
    if (cnt == 0) atomicAdd(&za, 1);
    int run = excl;
    for (int b = 0; b < NHB; ++b) {
        base[b * NCLS + t] = run;
        run += bh[b * NCLS + t];
    }
    __syncthreads();
    if (t == 0) { *nabsG = (float)za; *out = 0.0f; }
}

// Scatter: per-block LDS cursors seeded from deterministic bases.
__global__ __launch_bounds__(256) void k_scatter(
    const int* __restrict__ tgt, const int* __restrict__ base, int* __restrict__ ridx) {
    __shared__ int cur[NCLS];
    int t = threadIdx.x;
    int b = blockIdx.x;
    cur[t] = base[b * NCLS + t];
    cur[t + 256] = base[b * NCLS + t + 256];
    __syncthreads();
    int r0 = b * (NROWS / NHB);
    for (int i = t; i < NROWS / NHB; i += 256) {
        int row = r0 + i;
        int c = tgt[row];
        int pos = atomicAdd(&cur[c], 1);
        ridx[pos] = row;
    }
}

// Per-class mean + L2-normalize -> bf16 centers + analytic pos-sum into out.
__global__ __launch_bounds__(512) void k_centers(
    const unsigned short* __restrict__ xb, const int* __restrict__ ridx,
    const int* __restrict__ counts, const int* __restrict__ offs,
    unsigned short* __restrict__ cen, float* __restrict__ out) {
    __shared__ float2 sP[8][64];
    int t = threadIdx.x, w = t >> 6, l = t & 63;
    int cl = blockIdx.x;
    int cnt = counts[cl], start = offs[cl];
    const uint32_t* xb32 = (const uint32_t*)xb;
    float a0 = 0.0f, a1 = 0.0f;
    int per = (cnt + 7) >> 3;
    int lo = w * per, hi = min(cnt, lo + per);
    int i = lo;
    for (; i + 8 <= hi; i += 8) {
        int id[8]; uint32_t v[8];
#pragma unroll
        for (int j = 0; j < 8; ++j) id[j] = ridx[start + i + j];
#pragma unroll
        for (int j = 0; j < 8; ++j) v[j] = xb32[(size_t)id[j] * 64 + l];
#pragma unroll
        for (int j = 0; j < 8; ++j) { a0 += bflo(v[j]); a1 += bfhi(v[j]); }
    }
    for (; i < hi; ++i) {
        uint32_t v = xb32[(size_t)ridx[start + i] * 64 + l];
        a0 += bflo(v); a1 += bfhi(v);
    }
    sP[w][l] = make_float2(a0, a1);
    __syncthreads();
    if (w == 0) {
        float c0 = 0.0f, c1 = 0.0f;
#pragma unroll
        for (int q = 0; q < 8; ++q) { c0 += sP[q][l].x; c1 += sP[q][l].y; }
        float fc = fmaxf((float)cnt, 1.0f);
        c0 /= fc; c1 /= fc;
        float ss = c0 * c0 + c1 * c1;
        for (int off = 1; off < 64; off <<= 1) ss += __shfl_xor(ss, off);
        float inv = 1.0f / fmaxf(sqrtf(ss), 1e-12f);
        ushort2 o;
        o.x = f2bf(c0 * inv); o.y = f2bf(c1 * inv);
        *reinterpret_cast<ushort2*>(cen + (size_t)cl * DDIM + l * 2) = o;
        if (l == 0)
            atomicAdd(out, -(float)cnt * sqrtf(ss) * (INV_BETA / (float)NROWS));
    }
}

// K4 v5: 256 blocks x 16 waves. Staging via global_load_lds (linear LDS dest,
// inverse-swizzled global source), issued BEFORE the MFMA phase -> loads overlap
// compute; barrier's vmcnt(0) drains. 2 barriers/tile. Reads keep XOR swizzle.
__global__ __launch_bounds__(1024) void k4_loss(
    const unsigned short* __restrict__ xb, const unsigned short* __restrict__ cen,
    const float* __restrict__ nabsG, float* __restrict__ out) {
    extern __shared__ char lds[];
    char* xL0 = lds;                        // 32768
    char* xL1 = lds + 32768;                // 32768
    float* denP = (float*)(lds + 65536);    // 16*128 f32 = 8192
    float* wsum = (float*)(lds + 73728);    // 2 f32
    int t = threadIdx.x, w = t >> 6, l = t & 63;
    int lm = l & 15, lk = l >> 4;
    float nabs = *nabsG;

    v8bf afr[2][4];
#pragma unroll
    for (int m = 0; m < 2; ++m)
#pragma unroll
        for (int kc = 0; kc < 4; ++kc) {
            int arow = w * 32 + m * 16 + lm;
            afr[m][kc] = *reinterpret_cast<const v8bf*>(cen + (size_t)arow * DDIM + kc * 32 + lk * 8);
        }

    int block0 = blockIdx.x * 1024;
    const char* xbB = (const char*)xb + (size_t)block0 * 256;

    // tile-invariant staging offsets: linear chunk C -> stored pos holds orig
    // chunk (C&15)^(srow&7); src byte = srow*256 + (((C&15)^(srow&7))<<4).
    int C0 = w * 128 + l;
    int C1 = C0 + 64;
    int so0 = (C0 >> 4) * 256 + ((((C0 & 15) ^ ((C0 >> 4) & 7))) << 4);
    int so1 = (C1 >> 4) * 256 + ((((C1 & 15) ^ ((C1 >> 4) & 7))) << 4);
    int dw = w * 2048;  // wave-uniform LDS byte base (phase0); phase1 = +1024

    // prologue: stage tile 0 into xL0
    GLL16(xbB + so0, xL0 + dw);
    GLL16(xbB + so1, xL0 + dw + 1024);
    float lossAcc = 0.0f;
    asm volatile("s_waitcnt vmcnt(0)" ::: "memory");
    __syncthreads();

    for (int tile = 0; tile < 8; ++tile) {
        char* xc = (tile & 1) ? xL1 : xL0;
        char* xn = (tile & 1) ? xL0 : xL1;
        if (tile < 7) {
            const char* s = xbB + (size_t)(tile + 1) * 32768;
            GLL16(s + so0, xn + dw);
            GLL16(s + so1, xn + dw + 1024);
        }

#pragma unroll
        for (int h = 0; h < 2; ++h) {
            v4f acc[2][4];
            v4f zero = {0.0f, 0.0f, 0.0f, 0.0f};
#pragma unroll
            for (int m = 0; m < 2; ++m)
#pragma unroll
                for (int n = 0; n < 4; ++n) acc[m][n] = zero;

#pragma unroll
            for (int kc = 0; kc < 4; ++kc) {
                int kb = kc * 64 + lk * 16;
                v8bf b[4];
#pragma unroll
                for (int n = 0; n < 4; ++n) {
                    int brow = h * 64 + n * 16 + lm;
                    b[n] = *reinterpret_cast<const v8bf*>(xc + brow * 256 + (kb ^ ((brow & 7) << 4)));
                }
#pragma unroll
                for (int m = 0; m < 2; ++m)
#pragma unroll
                    for (int n = 0; n < 4; ++n)
                        acc[m][n] = __builtin_amdgcn_mfma_f32_16x16x32_bf16(afr[m][kc], b[n], acc[m][n], 0, 0, 0);
            }

#pragma unroll
            for (int n = 0; n < 4; ++n) {
                float se = 0.0f;
#pragma unroll
                for (int m = 0; m < 2; ++m) {
#pragma unroll
                    for (int rr = 0; rr < 4; ++rr)
                        se += __builtin_amdgcn_exp2f(acc[m][n][rr] * EXP2_SCALE);
                }
                se += __shfl_xor(se, 16); se += __shfl_xor(se, 32);
                if (l < 16) denP[w * 128 + h * 64 + n * 16 + lm] = se;
            }
        }
        asm volatile("s_waitcnt vmcnt(0)" ::: "memory");
        __syncthreads();  // denP complete; staging loads drained -> xn ready
        if (t < 128) {
            float den = 0.0f;
#pragma unroll
            for (int q = 0; q < 16; ++q) den += denP[q * 128 + t];
            lossAcc += __logf(den - nabs);
        }
        __syncthreads();  // protect denP before next tile's epilogue
    }
    if (t < 128) {
#pragma unroll
        for (int off = 1; off < 64; off <<= 1) lossAcc += __shfl_xor(lossAcc, off);
        if (l == 0) wsum[w] = lossAcc;
    }
    __syncthreads();
    if (t == 0) atomicAdd(out, (wsum[0] + wsum[1]) * (1.0f / NROWS));
}

extern "C" void kernel_launch(void* const* d_in, const int* in_sizes, int n_in,
                              void* d_out, int out_size, void* d_ws, size_t ws_size,
                              hipStream_t stream) {
    const float* in = (const float*)d_in[0];
    const int* tgt = (const int*)d_in[1];
    float* out = (float*)d_out;
    char* ws = (char*)d_ws;
    unsigned short* xb = (unsigned short*)(ws);              // 67108864 B
    int* counts = (int*)(ws + 67108864);                     // 2048 B
    int* offs = (int*)(ws + 67110912);                       // 2048 B
    float* nabsG = (float*)(ws + 67112960);                  // 256 B (pad)
    unsigned short* cen = (unsigned short*)(ws + 67115264);  // 131072 B
    int* ridx = (int*)(ws + 67246336);                       // 1048576 B
    int* bh = (int*)(ws + 68294912);                         // 131072 B (NHB=64)
    int* base = (int*)(ws + 68557056);                       // 131072 B

    (void)hipFuncSetAttribute((const void*)k4_loss,
                              hipFuncAttributeMaxDynamicSharedMemorySize, 73792);

    hipLaunchKernelGGL(k1_normalize, dim3(8192 + NHB), dim3(256), 0, stream, in, tgt, xb, bh);
    hipLaunchKernelGGL(k_prefix, dim3(1), dim3(512), 0, stream, bh, counts, offs, base, nabsG, out);
    hipLaunchKernelGGL(k_scatter, dim3(NHB), dim3(256), 0, stream, tgt, base, ridx);
    hipLaunchKernelGGL(k_centers, dim3(NCLS), dim3(512), 0, stream, xb, ridx, counts, offs, cen, out);
    hipLaunchKernelGGL(k4_loss, dim3(256), dim3(1024), 73792, stream, xb, cen, nabsG, out);
}

// Round 14
// 111.450 us; speedup vs baseline: 1.2453x; 1.0125x over previous
//
#include <hip/hip_runtime.h>
#include <stdint.h>

#define NROWS 262144
#define DDIM 128
#define NCLS 512
#define NHB 64  // hist/scatter blocks
constexpr float INV_BETA = 10.0f;
constexpr float EXP2_SCALE = 14.426950408889634f;  // 10 * log2(e)

typedef __bf16 v8bf __attribute__((ext_vector_type(8)));
typedef float v4f __attribute__((ext_vector_type(4)));

__device__ inline unsigned short f2bf(float f) {
    uint32_t u = __builtin_bit_cast(uint32_t, f);
    u += 0x7FFFu + ((u >> 16) & 1u);
    return (unsigned short)(u >> 16);
}
__device__ inline float bflo(uint32_t u) { return __builtin_bit_cast(float, u << 16); }
__device__ inline float bfhi(uint32_t u) { return __builtin_bit_cast(float, u & 0xFFFF0000u); }

// global_load_lds: wave-uniform LDS base + lane*16; pre-swizzled global source.
#define GLL16(gsrc, ldst)                                                        \
    __builtin_amdgcn_global_load_lds(                                            \
        (const __attribute__((address_space(1))) void*)(uintptr_t)(gsrc),        \
        (__attribute__((address_space(3))) void*)(uintptr_t)(ldst), 16, 0, 0)

// K1 v5: streaming L2-normalize fp32 -> bf16 (blocks 0..8191); class histogram
// fused as blocks 8192..8192+NHB-1.
__global__ __launch_bounds__(256) void k1_normalize(
    const float* __restrict__ in, const int* __restrict__ tgt,
    unsigned short* __restrict__ xb, int* __restrict__ bh) {
    __shared__ int h[NCLS];
    int t = threadIdx.x;
    if (blockIdx.x >= 8192) {
        int b = blockIdx.x - 8192;
        for (int i = t; i < NCLS; i += 256) h[i] = 0;
        __syncthreads();
        int base = b * (NROWS / NHB);
        for (int i = base + t; i < base + NROWS / NHB; i += 256)
            atomicAdd(&h[tgt[i]], 1);
        __syncthreads();
        for (int i = t; i < NCLS; i += 256)
            bh[b * NCLS + i] = h[i];
        return;
    }
    int w = t >> 6;
    int half = (t & 63) >> 5;
    int lane32 = t & 31;
    int hw = blockIdx.x * 8 + w * 2 + half;
    int r0 = hw * 4;
    float4 v[4];
#pragma unroll
    for (int j = 0; j < 4; ++j)
        v[j] = *reinterpret_cast<const float4*>(in + (size_t)(r0 + j) * DDIM + lane32 * 4);
    float s[4];
#pragma unroll
    for (int j = 0; j < 4; ++j)
        s[j] = v[j].x * v[j].x + v[j].y * v[j].y + v[j].z * v[j].z + v[j].w * v[j].w;
#pragma unroll
    for (int off = 1; off < 32; off <<= 1) {
#pragma unroll
        for (int j = 0; j < 4; ++j) s[j] += __shfl_xor(s[j], off);
    }
#pragma unroll
    for (int j = 0; j < 4; ++j) {
        float iv = rsqrtf(fmaxf(s[j], 1e-24f));
        ushort4 o;
        o.x = f2bf(v[j].x * iv); o.y = f2bf(v[j].y * iv);
        o.z = f2bf(v[j].z * iv); o.w = f2bf(v[j].w * iv);
        *reinterpret_cast<ushort4*>(xb + (size_t)(r0 + j) * DDIM + lane32 * 4) = o;
    }
}

// Prefix: counts, class offsets, n_absent, per-block bases; zero out.
__global__ __launch_bounds__(512) void k_prefix(
    const int* __restrict__ bh, int* __restrict__ counts, int* __restrict__ offs,
    int* __restrict__ base, float* __restrict__ nabsG, float* __restrict__ out) {
    __shared__ int sc[NCLS];
    __shared__ int za;
    int t = threadIdx.x;
    int cnt = 0;
#pragma unroll 8
    for (int b = 0; b < NHB; ++b) cnt += bh[b * NCLS + t];
    counts[t] = cnt;
    sc[t] = cnt;
    if (t == 0) za = 0;
    __syncthreads();
    for (int off = 1; off < NCLS; off <<= 1) {
        int v = (t >= off) ? sc[t - off] : 0;
        __syncthreads();
        sc[t] += v;
        __syncthreads();
    }
    int excl = sc[t] - cnt;
    offs[t] = excl;
    if (cnt == 0) atomicAdd(&za, 1);
    int run = excl;
    for (int b = 0; b < NHB; ++b) {
        base[b * NCLS + t] = run;
        run += bh[b * NCLS + t];
    }
    __syncthreads();
    if (t == 0) { *nabsG = (float)za; *out = 0.0f; }
}

// Scatter: per-block LDS cursors seeded from deterministic bases.
__global__ __launch_bounds__(256) void k_scatter(
    const int* __restrict__ tgt, const int* __restrict__ base, int* __restrict__ ridx) {
    __shared__ int cur[NCLS];
    int t = threadIdx.x;
    int b = blockIdx.x;
    cur[t] = base[b * NCLS + t];
    cur[t + 256] = base[b * NCLS + t + 256];
    __syncthreads();
    int r0 = b * (NROWS / NHB);
    for (int i = t; i < NROWS / NHB; i += 256) {
        int row = r0 + i;
        int c = tgt[row];
        int pos = atomicAdd(&cur[c], 1);
        ridx[pos] = row;
    }
}

// Per-class mean + L2-normalize -> bf16 centers PRE-SCALED by 10*log2(e)
// (so k4's MFMA acc is directly the exp2 argument). Analytic pos-sum into out.
__global__ __launch_bounds__(512) void k_centers(
    const unsigned short* __restrict__ xb, const int* __restrict__ ridx,
    const int* __restrict__ counts, const int* __restrict__ offs,
    unsigned short* __restrict__ cen, float* __restrict__ out) {
    __shared__ float2 sP[8][64];
    int t = threadIdx.x, w = t >> 6, l = t & 63;
    int cl = blockIdx.x;
    int cnt = counts[cl], start = offs[cl];
    const uint32_t* xb32 = (const uint32_t*)xb;
    float a0 = 0.0f, a1 = 0.0f;
    int per = (cnt + 7) >> 3;
    int lo = w * per, hi = min(cnt, lo + per);
    int i = lo;
    for (; i + 8 <= hi; i += 8) {
        int id[8]; uint32_t v[8];
#pragma unroll
        for (int j = 0; j < 8; ++j) id[j] = ridx[start + i + j];
#pragma unroll
        for (int j = 0; j < 8; ++j) v[j] = xb32[(size_t)id[j] * 64 + l];
#pragma unroll
        for (int j = 0; j < 8; ++j) { a0 += bflo(v[j]); a1 += bfhi(v[j]); }
    }
    for (; i < hi; ++i) {
        uint32_t v = xb32[(size_t)ridx[start + i] * 64 + l];
        a0 += bflo(v); a1 += bfhi(v);
    }
    sP[w][l] = make_float2(a0, a1);
    __syncthreads();
    if (w == 0) {
        float c0 = 0.0f, c1 = 0.0f;
#pragma unroll
        for (int q = 0; q < 8; ++q) { c0 += sP[q][l].x; c1 += sP[q][l].y; }
        float fc = fmaxf((float)cnt, 1.0f);
        c0 /= fc; c1 /= fc;
        float ss = c0 * c0 + c1 * c1;
        for (int off = 1; off < 64; off <<= 1) ss += __shfl_xor(ss, off);
        float inv = EXP2_SCALE / fmaxf(sqrtf(ss), 1e-12f);
        ushort2 o;
        o.x = f2bf(c0 * inv); o.y = f2bf(c1 * inv);
        *reinterpret_cast<ushort2*>(cen + (size_t)cl * DDIM + l * 2) = o;
        if (l == 0)
            atomicAdd(out, -(float)cnt * sqrtf(ss) * (INV_BETA / (float)NROWS));
    }
}

// K4 v6: 256 blocks x 16 waves. gll staging; exp2 direct (centers pre-scaled);
// den-reduce parallelized across all 16 waves; denP double-buffered -> ONE
// barrier per tile.
__global__ __launch_bounds__(1024) void k4_loss(
    const unsigned short* __restrict__ xb, const unsigned short* __restrict__ cen,
    const float* __restrict__ nabsG, float* __restrict__ out) {
    extern __shared__ char lds[];
    char* xL0 = lds;                        // 32768
    char* xL1 = lds + 32768;                // 32768
    float* denP = (float*)(lds + 65536);    // 2 x 16 x 128 f32 = 16384
    float* wsum = (float*)(lds + 81920);    // 16 f32
    int t = threadIdx.x, w = t >> 6, l = t & 63;
    int lm = l & 15, lk = l >> 4;
    float nabs = *nabsG;

    v8bf afr[2][4];
#pragma unroll
    for (int m = 0; m < 2; ++m)
#pragma unroll
        for (int kc = 0; kc < 4; ++kc) {
            int arow = w * 32 + m * 16 + lm;
            afr[m][kc] = *reinterpret_cast<const v8bf*>(cen + (size_t)arow * DDIM + kc * 32 + lk * 8);
        }

    int block0 = blockIdx.x * 1024;
    const char* xbB = (const char*)xb + (size_t)block0 * 256;

    int C0 = w * 128 + l;
    int C1 = C0 + 64;
    int so0 = (C0 >> 4) * 256 + ((((C0 & 15) ^ ((C0 >> 4) & 7))) << 4);
    int so1 = (C1 >> 4) * 256 + ((((C1 & 15) ^ ((C1 >> 4) & 7))) << 4);
    int dw = w * 2048;

    GLL16(xbB + so0, xL0 + dw);
    GLL16(xbB + so1, xL0 + dw + 1024);
    float lossAcc = 0.0f;
    // reduce-lane mapping: wave w owns samples [w*8, w*8+8)
    int rs = w * 8 + (l >> 3);   // sample slot 0..127
    int rq = (l & 7) * 2;        // q pair
    asm volatile("s_waitcnt vmcnt(0)" ::: "memory");
    __syncthreads();

    for (int tile = 0; tile < 8; ++tile) {
        char* xc = (tile & 1) ? xL1 : xL0;
        char* xn = (tile & 1) ? xL0 : xL1;
        float* dp = denP + (tile & 1) * 2048;
        if (tile < 7) {
            const char* s = xbB + (size_t)(tile + 1) * 32768;
            GLL16(s + so0, xn + dw);
            GLL16(s + so1, xn + dw + 1024);
        }

#pragma unroll
        for (int h = 0; h < 2; ++h) {
            v4f acc[2][4];
            v4f zero = {0.0f, 0.0f, 0.0f, 0.0f};
#pragma unroll
            for (int m = 0; m < 2; ++m)
#pragma unroll
                for (int n = 0; n < 4; ++n) acc[m][n] = zero;

#pragma unroll
            for (int kc = 0; kc < 4; ++kc) {
                int kb = kc * 64 + lk * 16;
                v8bf b[4];
#pragma unroll
                for (int n = 0; n < 4; ++n) {
                    int brow = h * 64 + n * 16 + lm;
                    b[n] = *reinterpret_cast<const v8bf*>(xc + brow * 256 + (kb ^ ((brow & 7) << 4)));
                }
#pragma unroll
                for (int m = 0; m < 2; ++m)
#pragma unroll
                    for (int n = 0; n < 4; ++n)
                        acc[m][n] = __builtin_amdgcn_mfma_f32_16x16x32_bf16(afr[m][kc], b[n], acc[m][n], 0, 0, 0);
            }

#pragma unroll
            for (int n = 0; n < 4; ++n) {
                float se = 0.0f;
#pragma unroll
                for (int m = 0; m < 2; ++m) {
#pragma unroll
                    for (int rr = 0; rr < 4; ++rr)
                        se += __builtin_amdgcn_exp2f(acc[m][n][rr]);
                }
                se += __shfl_xor(se, 16); se += __shfl_xor(se, 32);
                if (l < 16) dp[w * 128 + h * 64 + n * 16 + lm] = se;
            }
        }
        asm volatile("s_waitcnt vmcnt(0)" ::: "memory");
        __syncthreads();  // denP[par] complete; staged xn drained
        // all-wave reduce: 8 lanes per sample slot
        float den = dp[rq * 128 + rs] + dp[(rq + 1) * 128 + rs];
        den += __shfl_xor(den, 1);
        den += __shfl_xor(den, 2);
        den += __shfl_xor(den, 4);
        if ((l & 7) == 0) lossAcc += __logf(den - nabs);
        // no second barrier: next tile writes the other denP buffer
    }
    lossAcc += __shfl_xor(lossAcc, 8);
    lossAcc += __shfl_xor(lossAcc, 16);
    lossAcc += __shfl_xor(lossAcc, 32);
    if (l == 0) wsum[w] = lossAcc;
    __syncthreads();
    if (t == 0) {
        float s = 0.0f;
#pragma unroll
        for (int q = 0; q < 16; ++q) s += wsum[q];
        atomicAdd(out, s * (1.0f / NROWS));
    }
}

extern "C" void kernel_launch(void* const* d_in, const int* in_sizes, int n_in,
                              void* d_out, int out_size, void* d_ws, size_t ws_size,
                              hipStream_t stream) {
    const float* in = (const float*)d_in[0];
    const int* tgt = (const int*)d_in[1];
    float* out = (float*)d_out;
    char* ws = (char*)d_ws;
    unsigned short* xb = (unsigned short*)(ws);              // 67108864 B
    int* counts = (int*)(ws + 67108864);                     // 2048 B
    int* offs = (int*)(ws + 67110912);                       // 2048 B
    float* nabsG = (float*)(ws + 67112960);                  // 256 B (pad)
    unsigned short* cen = (unsigned short*)(ws + 67115264);  // 131072 B
    int* ridx = (int*)(ws + 67246336);                       // 1048576 B
    int* bh = (int*)(ws + 68294912);                         // 131072 B (NHB=64)
    int* base = (int*)(ws + 68557056);                       // 131072 B

    (void)hipFuncSetAttribute((const void*)k4_loss,
                              hipFuncAttributeMaxDynamicSharedMemorySize, 81984);

    hipLaunchKernelGGL(k1_normalize, dim3(8192 + NHB), dim3(256), 0, stream, in, tgt, xb, bh);
    hipLaunchKernelGGL(k_prefix, dim3(1), dim3(512), 0, stream, bh, counts, offs, base, nabsG, out);
    hipLaunchKernelGGL(k_scatter, dim3(NHB), dim3(256), 0, stream, tgt, base, ridx);
    hipLaunchKernelGGL(k_centers, dim3(NCLS), dim3(512), 0, stream, xb, ridx, counts, offs, cen, out);
    hipLaunchKernelGGL(k4_loss, dim3(256), dim3(1024), 81984, stream, xb, cen, nabsG, out);
}